// Round 6
// baseline (550.043 us; speedup 1.0000x reference)
//
#include <hip/hip_runtime.h>

// GCN 2-layer. N=250000, E=4000000, 18 -> 16 -> 1.
// Bucket-binned edge list (256 dst nodes/bucket, NB=977) + per-bucket LDS
// accumulators. No fp global atomics. agg1 uses 1 lane per edge with float4
// row gathers: one wave instruction = 64 distinct line requests (MLP fix for
// R5's 613 GB/s latency wall: ~1 outstanding line/wave).
//
// out[d] = dis[d] * (sum_{s->d} hs[s] + hs[d]) + bias, hs pre-scaled by dis.

#define NB_BITS 8
#define BN (1 << NB_BITS)       // 256 nodes per bucket
#define NBQ 1024                // scan/histogram width (>= NB=977)
#define BIN_TPB 512
#define BIN_CHUNK 8192
#define AGG_TPB 512
#define ASTRIDE 17              // LDS pad

// per-block LDS histogram of dst buckets -> global bcnt
__global__ void bhist_kernel(const int* __restrict__ dst, int* __restrict__ bcnt, int E, int NB_) {
    __shared__ int cnt[NBQ];
    int t = threadIdx.x;
    for (int i = t; i < NBQ; i += BIN_TPB) cnt[i] = 0;
    __syncthreads();
    int base = blockIdx.x * BIN_CHUNK;
    int end = min(base + BIN_CHUNK, E);
#pragma unroll 4
    for (int e = base + t; e < end; e += BIN_TPB)
        atomicAdd(&cnt[dst[e] >> NB_BITS], 1);
    __syncthreads();
    for (int i = t; i < NB_; i += BIN_TPB)
        if (cnt[i] > 0) atomicAdd(&bcnt[i], cnt[i]);
}

// exclusive scan of bcnt -> bstart, cursor (1024 threads)
__global__ void bscan_kernel(const int* __restrict__ bcnt, int* __restrict__ bstart,
                             int* __restrict__ cursor, int NB_) {
    __shared__ int s[NBQ];
    int t = threadIdx.x;
    int v = (t < NB_) ? bcnt[t] : 0;
    s[t] = v;
    __syncthreads();
    for (int off = 1; off < NBQ; off <<= 1) {
        int add = (t >= off) ? s[t - off] : 0;
        __syncthreads();
        s[t] += add;
        __syncthreads();
    }
    int excl = s[t] - v;
    if (t < NB_) {
        bstart[t] = excl;
        cursor[t] = excl;
        if (t == NB_ - 1) bstart[NB_] = excl + v;
    }
}

// place edges: block reserves private contiguous range per bucket, writes
// packed (src<<8 | dst&255) via LDS cursors. All lines single-block-owned.
__global__ void bplace_kernel(const int* __restrict__ src, const int* __restrict__ dst,
                              int* __restrict__ cursor, int* __restrict__ pairs, int E, int NB_) {
    __shared__ int cnt[NBQ];
    __shared__ int lofs[NBQ];
    int t = threadIdx.x;
    for (int i = t; i < NBQ; i += BIN_TPB) cnt[i] = 0;
    __syncthreads();
    int base = blockIdx.x * BIN_CHUNK;
    int end = min(base + BIN_CHUNK, E);
#pragma unroll 4
    for (int e = base + t; e < end; e += BIN_TPB)
        atomicAdd(&cnt[dst[e] >> NB_BITS], 1);
    __syncthreads();
    for (int i = t; i < NB_; i += BIN_TPB)
        if (cnt[i] > 0) lofs[i] = atomicAdd(&cursor[i], cnt[i]);
    __syncthreads();
#pragma unroll 4
    for (int e = base + t; e < end; e += BIN_TPB) {
        int d = dst[e];
        int sv = src[e];
        int b = d >> NB_BITS;
        int p = atomicAdd(&lofs[b], 1);
        pairs[p] = (sv << NB_BITS) | (d & (BN - 1));
    }
}

// per-bucket in-degree via LDS counters -> dis = rsqrt(deg+1)
__global__ void degdis_kernel(const int* __restrict__ pairs, const int* __restrict__ bstart,
                              float* __restrict__ dis, int N) {
    __shared__ int cnt[BN];
    int b = blockIdx.x, t = threadIdx.x;
    for (int i = t; i < BN; i += blockDim.x) cnt[i] = 0;
    __syncthreads();
    int s0 = bstart[b], s1 = bstart[b + 1];
#pragma unroll 4
    for (int e = s0 + t; e < s1; e += blockDim.x)
        atomicAdd(&cnt[pairs[e] & (BN - 1)], 1);
    __syncthreads();
    int nbase = b << NB_BITS;
    for (int i = t; i < BN; i += blockDim.x) {
        int n = nbase + i;
        if (n < N) dis[n] = rsqrtf((float)cnt[i] + 1.0f);
    }
}

// hs1[n,f] = (x[n] @ W1)[f] * dis[n]
__global__ void h1_kernel(const float* __restrict__ x, const float* __restrict__ W1,
                          const float* __restrict__ dis, float* __restrict__ hs1, int N) {
    __shared__ float w[18 * 16];
    for (int i = threadIdx.x; i < 18 * 16; i += blockDim.x) w[i] = W1[i];
    __syncthreads();
    int n = blockIdx.x * blockDim.x + threadIdx.x;
    if (n >= N) return;
    const float2* x2 = (const float2*)(x + (size_t)n * 18);
    float xv[18];
#pragma unroll
    for (int k = 0; k < 9; k++) {
        float2 v = x2[k];
        xv[2 * k] = v.x;
        xv[2 * k + 1] = v.y;
    }
    float d = dis[n];
    float acc[16];
#pragma unroll
    for (int f = 0; f < 16; f++) acc[f] = 0.0f;
#pragma unroll
    for (int k = 0; k < 18; k++) {
        float xk = xv[k];
#pragma unroll
        for (int f = 0; f < 16; f++) acc[f] = fmaf(xk, w[k * 16 + f], acc[f]);
    }
    float4* outp = (float4*)(hs1 + (size_t)n * 16);
#pragma unroll
    for (int q = 0; q < 4; q++) {
        float4 v;
        v.x = acc[q * 4 + 0] * d;
        v.y = acc[q * 4 + 1] * d;
        v.z = acc[q * 4 + 2] * d;
        v.w = acc[q * 4 + 3] * d;
        outp[q] = v;
    }
}

__device__ __forceinline__ void edge_accum(float* __restrict__ acc, const float4* __restrict__ hp,
                                           int dl, float4 v0, float4 v1, float4 v2, float4 v3) {
    float* a = acc + dl * ASTRIDE;
    atomicAdd(a + 0, v0.x);  atomicAdd(a + 1, v0.y);
    atomicAdd(a + 2, v0.z);  atomicAdd(a + 3, v0.w);
    atomicAdd(a + 4, v1.x);  atomicAdd(a + 5, v1.y);
    atomicAdd(a + 6, v1.z);  atomicAdd(a + 7, v1.w);
    atomicAdd(a + 8, v2.x);  atomicAdd(a + 9, v2.y);
    atomicAdd(a + 10, v2.z); atomicAdd(a + 11, v2.w);
    atomicAdd(a + 12, v3.x); atomicAdd(a + 13, v3.y);
    atomicAdd(a + 14, v3.z); atomicAdd(a + 15, v3.w);
}

// layer-1: 1 lane per edge, 4x float4 gather (64 lines/wave-instr), LDS accumulate.
// epilogue: relu + W2 dot + dis scale -> hs2
__global__ __launch_bounds__(AGG_TPB, 4) void agg1_kernel(
        const int* __restrict__ pairs, const int* __restrict__ bstart,
        const float* __restrict__ hs1, const float* __restrict__ dis,
        const float* __restrict__ b1, const float* __restrict__ W2,
        float* __restrict__ hs2, int N) {
    __shared__ float acc[BN * ASTRIDE];  // 17408 B
    int b = blockIdx.x, t = threadIdx.x;
    for (int i = t; i < BN * ASTRIDE; i += AGG_TPB) acc[i] = 0.f;
    __syncthreads();
    int s0 = bstart[b], s1 = bstart[b + 1];
    int e = s0 + t;
    // 2x unroll: 8 independent float4 gathers in flight per lane
    for (; e + AGG_TPB < s1; e += 2 * AGG_TPB) {
        int pva = pairs[e];
        int pvb = pairs[e + AGG_TPB];
        const float4* ha = (const float4*)(hs1 + ((size_t)(pva >> NB_BITS) << 4));
        const float4* hb = (const float4*)(hs1 + ((size_t)(pvb >> NB_BITS) << 4));
        float4 a0 = ha[0], a1 = ha[1], a2 = ha[2], a3 = ha[3];
        float4 b0 = hb[0], b1v = hb[1], b2 = hb[2], b3 = hb[3];
        edge_accum(acc, ha, pva & (BN - 1), a0, a1, a2, a3);
        edge_accum(acc, hb, pvb & (BN - 1), b0, b1v, b2, b3);
    }
    for (; e < s1; e += AGG_TPB) {
        int pv = pairs[e];
        const float4* hp = (const float4*)(hs1 + ((size_t)(pv >> NB_BITS) << 4));
        float4 v0 = hp[0], v1 = hp[1], v2 = hp[2], v3 = hp[3];
        edge_accum(acc, hp, pv & (BN - 1), v0, v1, v2, v3);
    }
    __syncthreads();
    int nbase = b << NB_BITS;
    int f = t & 15;
    float bbf = b1[f], wwf = W2[f];
    for (int nl = t >> 4; nl < BN; nl += AGG_TPB / 16) {
        int n = nbase + nl;
        float d = 0.f, p = 0.f;
        if (n < N) {
            d = dis[n];
            float self = hs1[(size_t)n * 16 + f];
            p = fmaxf(d * (acc[nl * ASTRIDE + f] + self) + bbf, 0.f) * wwf;
        }
        p += __shfl_xor(p, 1);
        p += __shfl_xor(p, 2);
        p += __shfl_xor(p, 4);
        p += __shfl_xor(p, 8);
        if (f == 0 && n < N) hs2[n] = p * d;
    }
}

// layer-2: per-bucket LDS accumulate of hs2 (1 lane/edge already), epilogue self+bias
__global__ __launch_bounds__(AGG_TPB, 4) void agg2_kernel(
        const int* __restrict__ pairs, const int* __restrict__ bstart,
        const float* __restrict__ hs2, const float* __restrict__ dis,
        const float* __restrict__ b2, float* __restrict__ out, int N) {
    __shared__ float acc[BN];
    int b = blockIdx.x, t = threadIdx.x;
    for (int i = t; i < BN; i += AGG_TPB) acc[i] = 0.f;
    __syncthreads();
    int s0 = bstart[b], s1 = bstart[b + 1];
    int e = s0 + t;
    for (; e + 3 * AGG_TPB < s1; e += 4 * AGG_TPB) {
        int pv0 = pairs[e];
        int pv1 = pairs[e + AGG_TPB];
        int pv2 = pairs[e + 2 * AGG_TPB];
        int pv3 = pairs[e + 3 * AGG_TPB];
        float v0 = hs2[pv0 >> NB_BITS];
        float v1 = hs2[pv1 >> NB_BITS];
        float v2 = hs2[pv2 >> NB_BITS];
        float v3 = hs2[pv3 >> NB_BITS];
        atomicAdd(&acc[pv0 & (BN - 1)], v0);
        atomicAdd(&acc[pv1 & (BN - 1)], v1);
        atomicAdd(&acc[pv2 & (BN - 1)], v2);
        atomicAdd(&acc[pv3 & (BN - 1)], v3);
    }
    for (; e < s1; e += AGG_TPB) {
        int pv = pairs[e];
        atomicAdd(&acc[pv & (BN - 1)], hs2[pv >> NB_BITS]);
    }
    __syncthreads();
    int nbase = b << NB_BITS;
    for (int i = t; i < BN; i += AGG_TPB) {
        int n = nbase + i;
        if (n < N) out[n] = dis[n] * (acc[i] + hs2[n]) + b2[0];
    }
}

extern "C" void kernel_launch(void* const* d_in, const int* in_sizes, int n_in,
                              void* d_out, int out_size, void* d_ws, size_t ws_size,
                              hipStream_t stream) {
    const float* x = (const float*)d_in[0];
    const int* edge_index = (const int*)d_in[1];
    const float* W1 = (const float*)d_in[2];
    const float* b1 = (const float*)d_in[3];
    const float* W2 = (const float*)d_in[4];
    const float* b2 = (const float*)d_in[5];
    float* out = (float*)d_out;

    const int N = in_sizes[0] / 18;
    const int E = in_sizes[1] / 2;
    const int* src = edge_index;
    const int* dst = edge_index + E;
    const int NB = (N + BN - 1) / BN;  // 977

    // ws layout (4B words): pairs[E], hs1[16N], hs2[N], dis[N],
    // bstart[NB+1], cursor[NB], bcnt[NB]  ~= 34 MB
    int* ws = (int*)d_ws;
    int* pairs = ws;
    float* hs1 = (float*)(ws + (size_t)E);
    float* hs2 = hs1 + (size_t)16 * N;
    float* dis = hs2 + N;
    int* bstart = (int*)(dis + N);
    int* cursor = bstart + NB + 1;
    int* bcnt = cursor + NB;

    hipMemsetAsync(bcnt, 0, NB * sizeof(int), stream);

    int binBlocks = (E + BIN_CHUNK - 1) / BIN_CHUNK;  // 489
    int nBlocksN = (N + 255) / 256;

    bhist_kernel<<<binBlocks, BIN_TPB, 0, stream>>>(dst, bcnt, E, NB);
    bscan_kernel<<<1, NBQ, 0, stream>>>(bcnt, bstart, cursor, NB);
    bplace_kernel<<<binBlocks, BIN_TPB, 0, stream>>>(src, dst, cursor, pairs, E, NB);
    degdis_kernel<<<NB, 256, 0, stream>>>(pairs, bstart, dis, N);
    h1_kernel<<<nBlocksN, 256, 0, stream>>>(x, W1, dis, hs1, N);
    agg1_kernel<<<NB, AGG_TPB, 0, stream>>>(pairs, bstart, hs1, dis, b1, W2, hs2, N);
    agg2_kernel<<<NB, AGG_TPB, 0, stream>>>(pairs, bstart, hs2, dis, b2, out, N);
}